// Round 20
// baseline (38.279 us; speedup 1.0000x reference)
//
#include <hip/hip_runtime.h>

// AnatomicalConsistencyLoss: fused separable-Sobel magnitude + cosine loss.
// pred/target (2,1,160,160,160) f32 -> scalar f32.
// R20 = R18 byte-for-byte (best: 32.55us; gload_lds double-buffered staging,
// one __syncthreads per plane, pending-sum z-stream, packed-v2 math, fused
// transcendentals, XCD-chunked swizzle, DC=16/1000 blocks) + single-kernel
// atomicAdd finalization (R16's lever, untangled from its unroll disaster):
// block leaders atomicAdd 0.2*(m-c)/N; block 0 adds the 0.2 constant;
// hipMemsetAsync zeroes d_out each launch (replay-deterministic, proven
// R16/R17). Saves the second launch + inter-kernel gap (~3us of bench time).
// R19's counted-vmcnt 3-deep staging was neutral -> reverted to R18 barrier.

constexpr int Dd = 160, Hh = 160, Ww = 160;
constexpr int TW = 32, TH = 16, DC = 16;
constexpr int NTX = Ww / TW;                 // 5
constexpr int NTY = Hh / TH;                 // 10
constexpr int NTZ = Dd / DC;                 // 10
constexpr int NBLOCKS = NTX * NTY * NTZ * 2; // 1000
constexpr int NXCD = 8;
constexpr int CHUNK = NBLOCKS / NXCD;        // 125
constexpr int PLANES = DC + 2;               // 18
constexpr int PLSZ = Hh * Ww;                // 25600
constexpr float INV_NVOX = 1.0f / 8192000.0f;

constexpr int SPANF = 40;                    // floats staged per row (x0-4..x0+36)
constexpr int SROWS = TH + 2;                // 18 rows staged per plane
constexpr int VOLF  = 768;                   // padded vol region: 3*1024B = 768 floats

typedef float v2 __attribute__((ext_vector_type(2)));
typedef float v4 __attribute__((ext_vector_type(4)));

#define GLD16(g, l)                                                     \
    __builtin_amdgcn_global_load_lds(                                   \
        (const __attribute__((address_space(1))) void*)(g),             \
        (__attribute__((address_space(3))) void*)(l), 16, 0, 0)

__global__ __launch_bounds__(256)
void acl_fused(const float* __restrict__ pred, const float* __restrict__ targ,
               float* __restrict__ out)
{
    __shared__ float sv[2][2][VOLF];   // [zbuf][vol][row*40+col], 12 KB
    __shared__ float rred[8];

    const int tid  = threadIdx.x;
    const int lane = tid & 63;
    const int wid  = tid >> 6;
    const int gx   = tid & 15;        // x-group of 2 output cols
    const int r    = tid >> 4;        // row 0..15

    // ---- XCD-chunked bijective swizzle + decode (zt fastest, wt, ht, b) ----
    const int bid = blockIdx.x;
    const int swz = (bid % NXCD) * CHUNK + bid / NXCD;
    const int zt  = swz % NTZ;
    const int t1  = swz / NTZ;
    const int wt  = t1 % NTX;
    const int t2  = t1 / NTX;
    const int ht  = t2 % NTY;
    const int b   = t2 / NTY;

    const int x0 = wt * TW, y0 = ht * TH;
    const int z0 = zt * DC;
    const size_t base = (size_t)b * ((size_t)Dd * PLSZ);
    const float* __restrict__ pv = pred + base;
    const float* __restrict__ tv = targ + base;

    // ---- staging constants (per-lane, loop-invariant) ----
    const int so   = (wid < 3 ? wid : 0) * 1024 + lane * 16;        // byte off in vol region
    int srow = so / 160;  if (srow > SROWS - 1) srow = SROWS - 1;   // row (160B rows)
    const int scol = (so % 160) >> 2;                               // float col, mult of 4
    int sgy = y0 - 1 + srow;  sgy = sgy < 0 ? 0 : (sgy > Hh - 1 ? Hh - 1 : sgy);
    int sgx = x0 - 4 + scol;  sgx = sgx < 0 ? 0 : (sgx > Ww - 4 ? Ww - 4 : sgx);
    const int splaneoff = sgy * Ww + sgx;
    const int ldsoff = wid * 256;                                   // floats

    // ---- consume constants ----
    const bool blkLo = (x0 == 0);
    const bool blkHi = (x0 + TW == Ww);
    const bool fixLo = blkLo && (gx == 0);
    const bool fixHi = blkHi && (gx == 15);
    const bool yokm  = (y0 + r - 1 >= 0);
    const bool yokp  = (y0 + r + 1 < Hh);
    const int  rb    = r * SPANF + 2 * gx + 3;   // col of X-1 in row r

    const v2 z2 = {0.f, 0.f};
    const v4 z4 = {0.f, 0.f, 0.f, 0.f};

    // streaming pending partial gradients (named v2 scalars only)
    v2 P1x = z2, P1y = z2, P1z = z2, P2x = z2, P2y = z2, P2z = z2;
    v2 T1x = z2, T1y = z2, T1z = z2, T2x = z2, T2y = z2, T2z = z2;
    v2 accm = z2, accc = z2;

    auto stage = [&](int p1, int buf) {   // stage plane p1 (z = z0-1+p1)
        if (wid < 3) {
            int gz = z0 - 1 + p1;
            gz = gz < 0 ? 0 : (gz > Dd - 1 ? Dd - 1 : gz);
            const float* gp = pv + (ptrdiff_t)gz * PLSZ + splaneoff;
            const float* gt = tv + (ptrdiff_t)gz * PLSZ + splaneoff;
            GLD16(gp, &sv[buf][0][ldsoff]);
            GLD16(gt, &sv[buf][1][ldsoff]);
        }
    };

    // read 4-float span [X-1..X+2] of one staged row; zero invalid floats
    auto loadRow = [&](const float* S, int idx, bool valid) -> v4 {
        v4 row;
        row.x = fixLo ? 0.f : S[idx];
        row.y = S[idx + 1];
        row.z = S[idx + 2];
        row.w = fixHi ? 0.f : S[idx + 3];
        if (!valid) row = z4;
        return row;
    };

    auto consumeVol = [&](const float* S, v2& A, v2& B, v2& C) {
        const v4 m = loadRow(S, rb,             yokm);
        const v4 c = loadRow(S, rb + SPANF,     true);
        const v4 p = loadRow(S, rb + 2 * SPANF, yokp);
        const v2 HSm = m.xy + 2.f*m.yz + m.zw;
        const v2 HDm = m.zw - m.xy;
        const v2 HS0 = c.xy + 2.f*c.yz + c.zw;
        const v2 HD0 = c.zw - c.xy;
        const v2 HSp = p.xy + 2.f*p.yz + p.zw;
        const v2 HDp = p.zw - p.xy;
        A = HSm + 2.f*HS0 + HSp;   // sm_y(sm_x) -> z-deriv path
        B = HDm + 2.f*HD0 + HDp;   // sm_y(d_x)  -> x-gradient
        C = HSp - HSm;             // d_y(sm_x)  -> y-gradient
    };

    stage(0, 0);
    __syncthreads();     // plane 0 staged

    #pragma unroll 1
    for (int p = 0; p < PLANES; ++p) {
        const int buf = p & 1;

        // issue next plane's staging: flies under this plane's compute
        if (p + 1 < PLANES) stage(p + 1, buf ^ 1);

        const bool zok = ((unsigned)(z0 - 1 + p) < (unsigned)Dd);   // wave-uniform

        v2 A, B, C;
        consumeVol(&sv[buf][0][0], A, B, C);
        if (!zok) { A = z2; B = z2; C = z2; }
        const v2 fpx = P1x + B, fpy = P1y + C, fpz = A - P1z;
        P1x = 2.f*B + P2x;  P1y = 2.f*C + P2y;  P1z = P2z;
        P2x = B;  P2y = C;  P2z = A;

        consumeVol(&sv[buf][1][0], A, B, C);
        if (!zok) { A = z2; B = z2; C = z2; }
        const v2 ftx = T1x + B, fty = T1y + C, ftz = A - T1z;
        T1x = 2.f*B + T2x;  T1y = 2.f*C + T2y;  T1z = T2z;
        T2x = B;  T2y = C;  T2z = A;

        if (p >= 2) {   // output plane z0 + (p-2) finalized
            // fused: (pm-tm)^2 = a+b-2*sqrt(ab);  rsq(np2)*rsq(nt2)=rsq(np2*nt2)
            const v2 np2 = fpx*fpx + fpy*fpy + fpz*fpz;
            const v2 nt2 = ftx*ftx + fty*fty + ftz*ftz;
            const v2 a  = np2 + 1e-8f;
            const v2 bb = nt2 + 1e-8f;
            const v2 ab = a * bb;
            v2 rt;
            rt.x = __builtin_amdgcn_sqrtf(ab.x);
            rt.y = __builtin_amdgcn_sqrtf(ab.y);
            accm += a + bb - 2.f*rt;
            const v2 dt = fpx*ftx + fpy*fty + fpz*ftz;
            v2 pr = np2 * nt2;
            pr.x = fmaxf(pr.x, 1e-30f);
            pr.y = fmaxf(pr.y, 1e-30f);
            v2 rq;
            rq.x = __builtin_amdgcn_rsqf(pr.x);
            rq.y = __builtin_amdgcn_rsqf(pr.y);
            accc += dt * rq;
        }

        // one barrier per plane: (a) next plane's staged data landed (vmcnt
        // drain), (b) all reads of buf done before iter p+2 overwrites it.
        __syncthreads();
    }

    // ---- block reduction, then one atomic per block ----
    float am = accm.x + accm.y;
    float ac = accc.x + accc.y;
    #pragma unroll
    for (int off = 32; off >= 1; off >>= 1) {
        am += __shfl_down(am, off);
        ac += __shfl_down(ac, off);
    }
    if ((tid & 63) == 0) { rred[wid] = am; rred[4 + wid] = ac; }
    __syncthreads();
    if (tid == 0) {
        const float m = rred[0] + rred[1] + rred[2] + rred[3];
        const float c = rred[4] + rred[5] + rred[6] + rred[7];
        // out = 0.2 + 0.2*(m_total - c_total)/NVOX; block 0 adds the constant
        float contrib = 0.2f * (m - c) * INV_NVOX;
        if (bid == 0) contrib += 0.2f;
        atomicAdd(out, contrib);
    }
}

extern "C" void kernel_launch(void* const* d_in, const int* in_sizes, int n_in,
                              void* d_out, int out_size, void* d_ws, size_t ws_size,
                              hipStream_t stream) {
    const float* pred = (const float*)d_in[0];
    const float* targ = (const float*)d_in[1];
    float* out = (float*)d_out;

    hipMemsetAsync(out, 0, sizeof(float), stream);   // graph-capturable
    acl_fused<<<NBLOCKS, 256, 0, stream>>>(pred, targ, out);
}

// Round 21
// 35.802 us; speedup vs baseline: 1.0692x; 1.0692x over previous
//
#include <hip/hip_runtime.h>

// AnatomicalConsistencyLoss: fused separable-Sobel magnitude + cosine loss.
// pred/target (2,1,160,160,160) f32 -> scalar f32.
// R21 = R18 structure (best bench 32.55us) with the 4-way LDS bank conflict
// fixed. R20's profile exposed SQ_LDS_BANK_CONFLICT=2.59M: row stride 40
// dwords === 8 (mod 32) keeps all 64 lanes of each scalar ds_read on ONE
// parity class of 16 banks (stride-2 cols x parity-preserving row offsets)
// -> 4-way conflict on every read. Fix: SPANF=41 (odd) -> row offsets mod 32
// = {0,9,18,27}, alternating parity -> 2 lanes/bank (free, m136). 41-dword
// rows can't be staged with 16B gload_lds chunks (rows straddle chunks), so
// staging switches to width-4 gload_lds: 4 issues x 192 dwords per volume,
// per-lane precomputed clamped source offsets (4 loop-invariant ints),
// linear LDS dest. Same double-buffer + one-__syncthreads-per-plane as R18.
// Finalize reverted to two-kernel (R20's memset+atomic cost ~6us).

constexpr int Dd = 160, Hh = 160, Ww = 160;
constexpr int TW = 32, TH = 16, DC = 16;
constexpr int NTX = Ww / TW;                 // 5
constexpr int NTY = Hh / TH;                 // 10
constexpr int NTZ = Dd / DC;                 // 10
constexpr int NBLOCKS = NTX * NTY * NTZ * 2; // 1000
constexpr int NXCD = 8;
constexpr int CHUNK = NBLOCKS / NXCD;        // 125
constexpr int PLANES = DC + 2;               // 18
constexpr int PLSZ = Hh * Ww;                // 25600
constexpr double NVOX = 2.0 * Dd * Hh * Ww;  // 8,192,000

constexpr int SPANF = 41;                    // ODD row stride (bank-conflict fix)
constexpr int SROWS = TH + 2;                // 18 rows staged per plane
constexpr int VOLD  = SROWS * SPANF;         // 738 dwords of real data
constexpr int VOLF  = 768;                   // padded region: 4 issues x 192

typedef float v2 __attribute__((ext_vector_type(2)));
typedef float v4 __attribute__((ext_vector_type(4)));

#define GLD4(g, l)                                                      \
    __builtin_amdgcn_global_load_lds(                                   \
        (const __attribute__((address_space(1))) void*)(g),             \
        (__attribute__((address_space(3))) void*)(l), 4, 0, 0)

__global__ __launch_bounds__(256)
void acl_partial(const float* __restrict__ pred, const float* __restrict__ targ,
                 float2* __restrict__ partial)
{
    __shared__ float sv[2][2][VOLF];   // [zbuf][vol][row*41+col], 12 KB
    __shared__ float rred[8];

    const int tid  = threadIdx.x;
    const int lane = tid & 63;
    const int wid  = tid >> 6;
    const int gx   = tid & 15;        // x-group of 2 output cols
    const int r    = tid >> 4;        // row 0..15

    // ---- XCD-chunked bijective swizzle + decode (zt fastest, wt, ht, b) ----
    const int bid = blockIdx.x;
    const int swz = (bid % NXCD) * CHUNK + bid / NXCD;
    const int zt  = swz % NTZ;
    const int t1  = swz / NTZ;
    const int wt  = t1 % NTX;
    const int t2  = t1 / NTX;
    const int ht  = t2 % NTY;
    const int b   = t2 / NTY;

    const int x0 = wt * TW, y0 = ht * TH;
    const int z0 = zt * DC;
    const size_t base = (size_t)b * ((size_t)Dd * PLSZ);
    const float* __restrict__ pv = pred + base;
    const float* __restrict__ tv = targ + base;

    // ---- staging constants: 4 per-lane clamped source offsets (invariant) ----
    const int wS = (wid < 3) ? wid : 0;
    int sp0, sp1, sp2, sp3;
    {
        auto mk = [&](int j) {
            int d = j * 192 + wS * 64 + lane;        // dword idx in vol region
            if (d > VOLD - 1) d = VOLD - 1;          // pad lanes: harmless dup
            const int row = d / SPANF;
            const int col = d - row * SPANF;
            int gy = y0 - 1 + row;  gy = gy < 0 ? 0 : (gy > Hh - 1 ? Hh - 1 : gy);
            int gxx = x0 - 4 + col; gxx = gxx < 0 ? 0 : (gxx > Ww - 1 ? Ww - 1 : gxx);
            return gy * Ww + gxx;
        };
        sp0 = mk(0); sp1 = mk(1); sp2 = mk(2); sp3 = mk(3);
    }
    const int ld0 = wS * 64;   // wave-uniform LDS dword base (HW adds lane*4 B)

    // ---- consume constants ----
    const bool blkLo = (x0 == 0);
    const bool blkHi = (x0 + TW == Ww);
    const bool fixLo = blkLo && (gx == 0);
    const bool fixHi = blkHi && (gx == 15);
    const bool yokm  = (y0 + r - 1 >= 0);
    const bool yokp  = (y0 + r + 1 < Hh);
    const int  rb    = r * SPANF + 2 * gx + 3;   // col of X-1 in row r

    const v2 z2 = {0.f, 0.f};
    const v4 z4 = {0.f, 0.f, 0.f, 0.f};

    // streaming pending partial gradients (named v2 scalars only)
    v2 P1x = z2, P1y = z2, P1z = z2, P2x = z2, P2y = z2, P2z = z2;
    v2 T1x = z2, T1y = z2, T1z = z2, T2x = z2, T2y = z2, T2z = z2;
    v2 accm = z2, accc = z2;

    auto stage = [&](int p1, int buf) {   // stage plane p1: 8 width-4 loads/wave
        if (wid < 3) {
            int gz = z0 - 1 + p1;
            gz = gz < 0 ? 0 : (gz > Dd - 1 ? Dd - 1 : gz);
            const float* gp = pv + (ptrdiff_t)gz * PLSZ;
            const float* gt = tv + (ptrdiff_t)gz * PLSZ;
            GLD4(gp + sp0, &sv[buf][0][ld0]);
            GLD4(gp + sp1, &sv[buf][0][ld0 + 192]);
            GLD4(gp + sp2, &sv[buf][0][ld0 + 384]);
            GLD4(gp + sp3, &sv[buf][0][ld0 + 576]);
            GLD4(gt + sp0, &sv[buf][1][ld0]);
            GLD4(gt + sp1, &sv[buf][1][ld0 + 192]);
            GLD4(gt + sp2, &sv[buf][1][ld0 + 384]);
            GLD4(gt + sp3, &sv[buf][1][ld0 + 576]);
        }
    };

    // read 4-float span [X-1..X+2] of one staged row; zero invalid floats
    auto loadRow = [&](const float* S, int idx, bool valid) -> v4 {
        v4 row;
        row.x = fixLo ? 0.f : S[idx];
        row.y = S[idx + 1];
        row.z = S[idx + 2];
        row.w = fixHi ? 0.f : S[idx + 3];
        if (!valid) row = z4;
        return row;
    };

    auto consumeVol = [&](const float* S, v2& A, v2& B, v2& C) {
        const v4 m = loadRow(S, rb,             yokm);
        const v4 c = loadRow(S, rb + SPANF,     true);
        const v4 p = loadRow(S, rb + 2 * SPANF, yokp);
        const v2 HSm = m.xy + 2.f*m.yz + m.zw;
        const v2 HDm = m.zw - m.xy;
        const v2 HS0 = c.xy + 2.f*c.yz + c.zw;
        const v2 HD0 = c.zw - c.xy;
        const v2 HSp = p.xy + 2.f*p.yz + p.zw;
        const v2 HDp = p.zw - p.xy;
        A = HSm + 2.f*HS0 + HSp;   // sm_y(sm_x) -> z-deriv path
        B = HDm + 2.f*HD0 + HDp;   // sm_y(d_x)  -> x-gradient
        C = HSp - HSm;             // d_y(sm_x)  -> y-gradient
    };

    stage(0, 0);
    __syncthreads();     // plane 0 staged

    #pragma unroll 1
    for (int p = 0; p < PLANES; ++p) {
        const int buf = p & 1;

        // issue next plane's staging: flies under this plane's compute
        if (p + 1 < PLANES) stage(p + 1, buf ^ 1);

        const bool zok = ((unsigned)(z0 - 1 + p) < (unsigned)Dd);   // wave-uniform

        v2 A, B, C;
        consumeVol(&sv[buf][0][0], A, B, C);
        if (!zok) { A = z2; B = z2; C = z2; }
        const v2 fpx = P1x + B, fpy = P1y + C, fpz = A - P1z;
        P1x = 2.f*B + P2x;  P1y = 2.f*C + P2y;  P1z = P2z;
        P2x = B;  P2y = C;  P2z = A;

        consumeVol(&sv[buf][1][0], A, B, C);
        if (!zok) { A = z2; B = z2; C = z2; }
        const v2 ftx = T1x + B, fty = T1y + C, ftz = A - T1z;
        T1x = 2.f*B + T2x;  T1y = 2.f*C + T2y;  T1z = T2z;
        T2x = B;  T2y = C;  T2z = A;

        if (p >= 2) {   // output plane z0 + (p-2) finalized
            // fused: (pm-tm)^2 = a+b-2*sqrt(ab);  rsq(np2)*rsq(nt2)=rsq(np2*nt2)
            const v2 np2 = fpx*fpx + fpy*fpy + fpz*fpz;
            const v2 nt2 = ftx*ftx + fty*fty + ftz*ftz;
            const v2 a  = np2 + 1e-8f;
            const v2 bb = nt2 + 1e-8f;
            const v2 ab = a * bb;
            v2 rt;
            rt.x = __builtin_amdgcn_sqrtf(ab.x);
            rt.y = __builtin_amdgcn_sqrtf(ab.y);
            accm += a + bb - 2.f*rt;
            const v2 dt = fpx*ftx + fpy*fty + fpz*ftz;
            v2 pr = np2 * nt2;
            pr.x = fmaxf(pr.x, 1e-30f);
            pr.y = fmaxf(pr.y, 1e-30f);
            v2 rq;
            rq.x = __builtin_amdgcn_rsqf(pr.x);
            rq.y = __builtin_amdgcn_rsqf(pr.y);
            accc += dt * rq;
        }

        // one barrier per plane: (a) next plane's staged data landed (vmcnt
        // drain), (b) all reads of buf done before iter p+2 overwrites it.
        __syncthreads();
    }

    // ---- block reduction ----
    float am = accm.x + accm.y;
    float ac = accc.x + accc.y;
    #pragma unroll
    for (int off = 32; off >= 1; off >>= 1) {
        am += __shfl_down(am, off);
        ac += __shfl_down(ac, off);
    }
    if ((tid & 63) == 0) { rred[wid] = am; rred[4 + wid] = ac; }
    __syncthreads();
    if (tid == 0) {
        const float m = rred[0] + rred[1] + rred[2] + rred[3];
        const float c = rred[4] + rred[5] + rred[6] + rred[7];
        partial[bid] = make_float2(m, c);
    }
}

__global__ __launch_bounds__(256)
void acl_final(const float2* __restrict__ partial, float* __restrict__ out)
{
    __shared__ double sm[256], sc[256];
    double m = 0.0, c = 0.0;
    for (int i = threadIdx.x; i < NBLOCKS; i += 256) {
        const float2 v = partial[i];
        m += (double)v.x;
        c += (double)v.y;
    }
    sm[threadIdx.x] = m;
    sc[threadIdx.x] = c;
    __syncthreads();
    #pragma unroll
    for (int s = 128; s >= 1; s >>= 1) {
        if (threadIdx.x < (unsigned)s) {
            sm[threadIdx.x] += sm[threadIdx.x + s];
            sc[threadIdx.x] += sc[threadIdx.x + s];
        }
        __syncthreads();
    }
    if (threadIdx.x == 0) {
        const double mag_loss = sm[0] / NVOX;
        const double dir_loss = 1.0 - sc[0] / NVOX;
        out[0] = (float)(0.2 * (mag_loss + dir_loss));
    }
}

extern "C" void kernel_launch(void* const* d_in, const int* in_sizes, int n_in,
                              void* d_out, int out_size, void* d_ws, size_t ws_size,
                              hipStream_t stream) {
    const float* pred = (const float*)d_in[0];
    const float* targ = (const float*)d_in[1];
    float* out = (float*)d_out;
    float2* partial = (float2*)d_ws;  // 1000 * 8 B = 8 KB

    acl_partial<<<NBLOCKS, 256, 0, stream>>>(pred, targ, partial);
    acl_final<<<1, 256, 0, stream>>>(partial, out);
}

// Round 22
// 31.192 us; speedup vs baseline: 1.2272x; 1.1478x over previous
//
#include <hip/hip_runtime.h>

// AnatomicalConsistencyLoss: fused separable-Sobel magnitude + cosine loss.
// pred/target (2,1,160,160,160) f32 -> scalar f32.
// R22 = R18 (best bench 32.55us: width-16 gload_lds staging, SPANF=40) with
// TWO PLANES PER BARRIER INTERVAL. Ledger shows profiled time flat at ~40us
// since R14 across register/LDS/pipelined variants -> binding term is the
// per-plane barrier quantum (~350cy compute between __syncthreads, x18).
// This round: 4 LDS plane-slots (24KB), prologue stages planes 0-1, each
// interval stages pp+2,pp+3 and computes pp,pp+1 (~700cy) before ONE
// barrier. Barriers 18->9; staging cover doubles (>L3 worst latency); the
// two planes' ds_reads interleave for ILP. R21's conflict fix reverted (0
// conflicts gained 0 wall time - latency-hidden; width-16 coalescing wins).
// Register state unchanged (named v2 scalars; slot index only touches LDS).
// Trip count 9: unroll PINNED (R16 lesson). Two-kernel finalize (R20 lesson).

constexpr int Dd = 160, Hh = 160, Ww = 160;
constexpr int TW = 32, TH = 16, DC = 16;
constexpr int NTX = Ww / TW;                 // 5
constexpr int NTY = Hh / TH;                 // 10
constexpr int NTZ = Dd / DC;                 // 10
constexpr int NBLOCKS = NTX * NTY * NTZ * 2; // 1000
constexpr int NXCD = 8;
constexpr int CHUNK = NBLOCKS / NXCD;        // 125
constexpr int PLANES = DC + 2;               // 18 (even: 9 two-plane intervals)
constexpr int PLSZ = Hh * Ww;                // 25600
constexpr double NVOX = 2.0 * Dd * Hh * Ww;  // 8,192,000

constexpr int SPANF = 40;                    // floats staged per row (x0-4..x0+36)
constexpr int SROWS = TH + 2;                // 18 rows staged per plane
constexpr int VOLF  = 768;                   // padded vol region: 3*1024B

typedef float v2 __attribute__((ext_vector_type(2)));
typedef float v4 __attribute__((ext_vector_type(4)));

#define GLD16(g, l)                                                     \
    __builtin_amdgcn_global_load_lds(                                   \
        (const __attribute__((address_space(1))) void*)(g),             \
        (__attribute__((address_space(3))) void*)(l), 16, 0, 0)

__global__ __launch_bounds__(256)
void acl_partial(const float* __restrict__ pred, const float* __restrict__ targ,
                 float2* __restrict__ partial)
{
    __shared__ float sv[4][2][VOLF];   // [plane-slot][vol][row*40+col], 24 KB
    __shared__ float rred[8];

    const int tid  = threadIdx.x;
    const int lane = tid & 63;
    const int wid  = tid >> 6;
    const int gx   = tid & 15;        // x-group of 2 output cols
    const int r    = tid >> 4;        // row 0..15

    // ---- XCD-chunked bijective swizzle + decode (zt fastest, wt, ht, b) ----
    const int bid = blockIdx.x;
    const int swz = (bid % NXCD) * CHUNK + bid / NXCD;
    const int zt  = swz % NTZ;
    const int t1  = swz / NTZ;
    const int wt  = t1 % NTX;
    const int t2  = t1 / NTX;
    const int ht  = t2 % NTY;
    const int b   = t2 / NTY;

    const int x0 = wt * TW, y0 = ht * TH;
    const int z0 = zt * DC;
    const size_t base = (size_t)b * ((size_t)Dd * PLSZ);
    const float* __restrict__ pv = pred + base;
    const float* __restrict__ tv = targ + base;

    // ---- staging constants (per-lane, loop-invariant) ----
    const int so   = (wid < 3 ? wid : 0) * 1024 + lane * 16;        // byte off in vol region
    int srow = so / 160;  if (srow > SROWS - 1) srow = SROWS - 1;   // row (160B rows)
    const int scol = (so % 160) >> 2;                               // float col, mult of 4
    int sgy = y0 - 1 + srow;  sgy = sgy < 0 ? 0 : (sgy > Hh - 1 ? Hh - 1 : sgy);
    int sgx = x0 - 4 + scol;  sgx = sgx < 0 ? 0 : (sgx > Ww - 4 ? Ww - 4 : sgx);
    const int splaneoff = sgy * Ww + sgx;
    const int ldsoff = wid * 256;                                   // floats

    // ---- consume constants ----
    const bool blkLo = (x0 == 0);
    const bool blkHi = (x0 + TW == Ww);
    const bool fixLo = blkLo && (gx == 0);
    const bool fixHi = blkHi && (gx == 15);
    const bool yokm  = (y0 + r - 1 >= 0);
    const bool yokp  = (y0 + r + 1 < Hh);
    const int  rb    = r * SPANF + 2 * gx + 3;   // col of X-1 in row r

    const v2 z2 = {0.f, 0.f};
    const v4 z4 = {0.f, 0.f, 0.f, 0.f};

    // streaming pending partial gradients (named v2 scalars only)
    v2 P1x = z2, P1y = z2, P1z = z2, P2x = z2, P2y = z2, P2z = z2;
    v2 T1x = z2, T1y = z2, T1z = z2, T2x = z2, T2y = z2, T2z = z2;
    v2 accm = z2, accc = z2;

    auto stage = [&](int p1, int slot) {   // stage plane p1 (z = z0-1+p1)
        if (wid < 3) {
            int gz = z0 - 1 + p1;
            gz = gz < 0 ? 0 : (gz > Dd - 1 ? Dd - 1 : gz);
            const float* gp = pv + (ptrdiff_t)gz * PLSZ + splaneoff;
            const float* gt = tv + (ptrdiff_t)gz * PLSZ + splaneoff;
            GLD16(gp, &sv[slot][0][ldsoff]);
            GLD16(gt, &sv[slot][1][ldsoff]);
        }
    };

    // read 4-float span [X-1..X+2] of one staged row; zero invalid floats
    auto loadRow = [&](const float* S, int idx, bool valid) -> v4 {
        v4 row;
        row.x = fixLo ? 0.f : S[idx];
        row.y = S[idx + 1];
        row.z = S[idx + 2];
        row.w = fixHi ? 0.f : S[idx + 3];
        if (!valid) row = z4;
        return row;
    };

    auto consumeVol = [&](const float* S, v2& A, v2& B, v2& C) {
        const v4 m = loadRow(S, rb,             yokm);
        const v4 c = loadRow(S, rb + SPANF,     true);
        const v4 p = loadRow(S, rb + 2 * SPANF, yokp);
        const v2 HSm = m.xy + 2.f*m.yz + m.zw;
        const v2 HDm = m.zw - m.xy;
        const v2 HS0 = c.xy + 2.f*c.yz + c.zw;
        const v2 HD0 = c.zw - c.xy;
        const v2 HSp = p.xy + 2.f*p.yz + p.zw;
        const v2 HDp = p.zw - p.xy;
        A = HSm + 2.f*HS0 + HSp;   // sm_y(sm_x) -> z-deriv path
        B = HDm + 2.f*HD0 + HDp;   // sm_y(d_x)  -> x-gradient
        C = HSp - HSm;             // d_y(sm_x)  -> y-gradient
    };

    auto doPlane = [&](int p, int slot) {
        const bool zok = ((unsigned)(z0 - 1 + p) < (unsigned)Dd);   // wave-uniform

        v2 A, B, C;
        consumeVol(&sv[slot][0][0], A, B, C);
        if (!zok) { A = z2; B = z2; C = z2; }
        const v2 fpx = P1x + B, fpy = P1y + C, fpz = A - P1z;
        P1x = 2.f*B + P2x;  P1y = 2.f*C + P2y;  P1z = P2z;
        P2x = B;  P2y = C;  P2z = A;

        consumeVol(&sv[slot][1][0], A, B, C);
        if (!zok) { A = z2; B = z2; C = z2; }
        const v2 ftx = T1x + B, fty = T1y + C, ftz = A - T1z;
        T1x = 2.f*B + T2x;  T1y = 2.f*C + T2y;  T1z = T2z;
        T2x = B;  T2y = C;  T2z = A;

        if (p >= 2) {   // output plane z0 + (p-2) finalized
            // fused: (pm-tm)^2 = a+b-2*sqrt(ab);  rsq(np2)*rsq(nt2)=rsq(np2*nt2)
            const v2 np2 = fpx*fpx + fpy*fpy + fpz*fpz;
            const v2 nt2 = ftx*ftx + fty*fty + ftz*ftz;
            const v2 a  = np2 + 1e-8f;
            const v2 bb = nt2 + 1e-8f;
            const v2 ab = a * bb;
            v2 rt;
            rt.x = __builtin_amdgcn_sqrtf(ab.x);
            rt.y = __builtin_amdgcn_sqrtf(ab.y);
            accm += a + bb - 2.f*rt;
            const v2 dt = fpx*ftx + fpy*fty + fpz*ftz;
            v2 pr = np2 * nt2;
            pr.x = fmaxf(pr.x, 1e-30f);
            pr.y = fmaxf(pr.y, 1e-30f);
            v2 rq;
            rq.x = __builtin_amdgcn_rsqf(pr.x);
            rq.y = __builtin_amdgcn_rsqf(pr.y);
            accc += dt * rq;
        }
    };

    // ---- prologue: stage the first two planes ----
    stage(0, 0);
    stage(1, 1);
    __syncthreads();

    #pragma unroll 1   // CRITICAL: rolled (trip count 9 is in unroll danger zone)
    for (int pp = 0; pp < PLANES; pp += 2) {
        // stage the NEXT interval's two planes; they fly under ~700cy compute
        if (pp + 2 < PLANES) stage(pp + 2, (pp + 2) & 3);
        if (pp + 3 < PLANES) stage(pp + 3, (pp + 3) & 3);

        doPlane(pp,     pp & 3);
        doPlane(pp + 1, (pp + 1) & 3);

        // one barrier per TWO planes: (a) staged data for next interval landed
        // (syncthreads drains vmcnt), (b) slots pp,pp+1 fully read before the
        // next interval's stage (pp+4 -> slot pp&3) overwrites them.
        __syncthreads();
    }

    // ---- block reduction ----
    float am = accm.x + accm.y;
    float ac = accc.x + accc.y;
    #pragma unroll
    for (int off = 32; off >= 1; off >>= 1) {
        am += __shfl_down(am, off);
        ac += __shfl_down(ac, off);
    }
    if ((tid & 63) == 0) { rred[wid] = am; rred[4 + wid] = ac; }
    __syncthreads();
    if (tid == 0) {
        const float m = rred[0] + rred[1] + rred[2] + rred[3];
        const float c = rred[4] + rred[5] + rred[6] + rred[7];
        partial[bid] = make_float2(m, c);
    }
}

__global__ __launch_bounds__(256)
void acl_final(const float2* __restrict__ partial, float* __restrict__ out)
{
    __shared__ double sm[256], sc[256];
    double m = 0.0, c = 0.0;
    for (int i = threadIdx.x; i < NBLOCKS; i += 256) {
        const float2 v = partial[i];
        m += (double)v.x;
        c += (double)v.y;
    }
    sm[threadIdx.x] = m;
    sc[threadIdx.x] = c;
    __syncthreads();
    #pragma unroll
    for (int s = 128; s >= 1; s >>= 1) {
        if (threadIdx.x < (unsigned)s) {
            sm[threadIdx.x] += sm[threadIdx.x + s];
            sc[threadIdx.x] += sc[threadIdx.x + s];
        }
        __syncthreads();
    }
    if (threadIdx.x == 0) {
        const double mag_loss = sm[0] / NVOX;
        const double dir_loss = 1.0 - sc[0] / NVOX;
        out[0] = (float)(0.2 * (mag_loss + dir_loss));
    }
}

extern "C" void kernel_launch(void* const* d_in, const int* in_sizes, int n_in,
                              void* d_out, int out_size, void* d_ws, size_t ws_size,
                              hipStream_t stream) {
    const float* pred = (const float*)d_in[0];
    const float* targ = (const float*)d_in[1];
    float* out = (float*)d_out;
    float2* partial = (float2*)d_ws;  // 1000 * 8 B = 8 KB

    acl_partial<<<NBLOCKS, 256, 0, stream>>>(pred, targ, partial);
    acl_final<<<1, 256, 0, stream>>>(partial, out);
}